// Round 8
// baseline (161.805 us; speedup 1.0000x reference)
//
#include <hip/hip_runtime.h>
#include <math.h>

#define BATCH 8
#define NPRED 8192
#define MPART 2048
#define NPTS  (BATCH * NPRED)     // 65536 queries
#define MTOT  (BATCH * MPART)     // 16384 partial points
#define PPL   32                  // points per lane (2048 / 64)
#define QPW   32                  // queries per wave
#define NNBLK (NPTS / QPW / 4)    // 512 blocks x 4 waves = 2048 waves
#define BASE_ALPHA 0.05f
#define EPS 1e-6f

// pt2[b][i][lane] = (-2x,-2y,-2z,|b|^2) of batch-b point m = lane*32 + i.
// Lane-major inner dim -> the nn kernel's 32 point loads are fully coalesced.
// near4[g] = (x,y,z,0) for single-dwordx4 nearest gathers. Also zeroes bmax.
__global__ __launch_bounds__(256) void prep_kernel(const float* __restrict__ partial,
                                                   float4* __restrict__ pt2,
                                                   float4* __restrict__ near4,
                                                   unsigned* __restrict__ bmax) {
    const int g = blockIdx.x * 256 + threadIdx.x;   // 64 blocks cover MTOT
    const int b = g >> 11, m = g & 2047;
    const float* p = partial + 3u * (unsigned)g;
    const float x = p[0], y = p[1], z = p[2];
    const int ln = m >> 5, i = m & 31;
    pt2[(((b << 5) + i) << 6) + ln] =
        make_float4(-2.0f * x, -2.0f * y, -2.0f * z, fmaf(x, x, fmaf(y, y, z * z)));
    near4[g] = make_float4(x, y, z, 0.0f);
    if (g < 16) bmax[g] = 0u;                        // 2 iters x 8 batches
}

// One wave = one independent worker: holds its batch's FULL 2048 points in
// VGPRs (32/lane, 128 regs), processes 32 consecutive queries. Query coords
// come from SGPRs (wave-uniform s_load). Inner loop: 3 fma + cmp + 2 cndmask
// per point — zero LDS, zero barriers. Cross-lane argmin: 6-step shfl_xor
// u64-min butterfly; key = (d2bits<<32)|m so ties pick lowest m (== jnp
// first-occurrence; per-lane strict '<' keeps earliest i; lanes hold
// m-contiguous chunks so (lane,i) order == m order).
__global__ __launch_bounds__(256, 2) void nn_kernel(
    const float* __restrict__ src,       // [B,N,3] query positions
    const float4* __restrict__ pt2,      // [MTOT] lane-major transformed points
    float* __restrict__ md_out,          // [NPTS]
    int*   __restrict__ idx_out,         // [NPTS] (index within batch)
    unsigned* __restrict__ bmax)         // [BATCH] max(min_dist) as uint bits
{
    const int lane = threadIdx.x & 63;
    int wgi = (blockIdx.x << 2) + (threadIdx.x >> 6);
    wgi = __builtin_amdgcn_readfirstlane(wgi);   // provably wave-uniform
    const int qbase = wgi << 5;                  // this wave's 32 queries
    const int b = qbase >> 13;                   // batch

    // Load my 32 points into registers (32 coalesced dwordx4 loads).
    float4 pt[PPL];
    const float4* psrc = pt2 + ((b << 5) << 6) + lane;
    #pragma unroll
    for (int i = 0; i < PPL; ++i) pt[i] = psrc[i << 6];

    const float* qsrc = src + 3 * qbase;         // uniform base -> s_load
    const int lane32 = lane << 5;

    float res_md = 0.0f; int res_idx = 0;
    float wmax = 0.0f;

    #pragma unroll 1
    for (int q = 0; q < QPW; ++q) {
        const float ax = qsrc[3 * q + 0];
        const float ay = qsrc[3 * q + 1];
        const float az = qsrc[3 * q + 2];
        // h = |b|^2 - 2 a.b  (order-identical to d^2; matches the reference's
        // a2 - 2ab + b2 expansion arithmetic)
        float best = 1e30f; int bi = 0;
        #pragma unroll
        for (int i = 0; i < PPL; ++i) {
            const float d = fmaf(pt[i].x, ax,
                            fmaf(pt[i].y, ay,
                            fmaf(pt[i].z, az, pt[i].w)));
            if (d < best) { best = d; bi = i; }   // strict <: earliest i wins
        }
        const float a2 = fmaf(ax, ax, fmaf(ay, ay, az * az));
        const float d2 = fmaxf(best + a2, 0.0f);  // nonneg -> uint-ordered bits
        unsigned long long key =
            ((unsigned long long)__float_as_uint(d2) << 32) |
            (unsigned)(lane32 | bi);
        #pragma unroll
        for (int o = 1; o < 64; o <<= 1) {
            const unsigned long long other = __shfl_xor(key, o, 64);
            if (other < key) key = other;         // u64 min == (d2, m) lex
        }
        const float md = sqrtf(__uint_as_float((unsigned)(key >> 32)));
        wmax = fmaxf(wmax, md);                   // uniform across lanes
        if (lane == q) { res_md = md; res_idx = (int)(key & 0xffffffffu); }
    }

    if (lane < 32) {
        md_out[qbase + lane]  = res_md;
        idx_out[qbase + lane] = res_idx;
    }
    if (lane == 0)
        atomicMax(bmax + b, __float_as_uint(wmax));  // exact, order-independent
}

// Blend: dst = src + alpha * (nearest - src).
__global__ __launch_bounds__(256) void update_kernel(
    const float* __restrict__ src,
    const float4* __restrict__ near4,
    const float* __restrict__ md,
    const int*   __restrict__ idx,
    const unsigned* __restrict__ bmax,
    float* __restrict__ dst)
{
    const int t = blockIdx.x * 256 + threadIdx.x;
    const int b = t >> 13;
    const float maxv = __uint_as_float(bmax[b]);
    const float alpha = BASE_ALPHA * (2.0f - md[t] / (maxv + EPS));
    const float4 nb = near4[(b << 11) + idx[t]];
    const float* p = src + 3u * (unsigned)t;
    const float px = p[0], py = p[1], pz = p[2];
    float* o = dst + 3u * (unsigned)t;
    o[0] = fmaf(alpha, nb.x - px, px);
    o[1] = fmaf(alpha, nb.y - py, py);
    o[2] = fmaf(alpha, nb.z - pz, pz);
}

extern "C" void kernel_launch(void* const* d_in, const int* in_sizes, int n_in,
                              void* d_out, int out_size, void* d_ws, size_t ws_size,
                              hipStream_t stream) {
    const float* pred    = (const float*)d_in[0];   // [8,8192,3] fp32
    const float* partial = (const float*)d_in[1];   // [8,2048,3] fp32
    float* out = (float*)d_out;

    char* ws = (char*)d_ws;
    float4*   pt2   = (float4*)ws;                  // 256 KB lane-major points
    float4*   near4 = (float4*)(ws + 262144);       // 256 KB
    float*    ref1  = (float*)(ws + 524288);        // 768 KB refined-1
    float*    md1   = (float*)(ws + 1310720);       // 256 KB
    int*      idx1  = (int*)(ws + 1572864);         // 256 KB
    unsigned* bmax  = (unsigned*)(ws + 1835008);    // 16 uints (2 iters x 8)

    prep_kernel<<<MTOT / 256, 256, 0, stream>>>(partial, pt2, near4, bmax);

    // Iter 1: NN on pred, then blend pred -> ref1
    nn_kernel<<<NNBLK, 256, 0, stream>>>(pred, pt2, md1, idx1, bmax);
    update_kernel<<<NPTS / 256, 256, 0, stream>>>(pred, near4, md1, idx1, bmax, ref1);

    // Iter 2: NN on ref1, then blend ref1 -> out
    nn_kernel<<<NNBLK, 256, 0, stream>>>(ref1, pt2, md1, idx1, bmax + 8);
    update_kernel<<<NPTS / 256, 256, 0, stream>>>(ref1, near4, md1, idx1, bmax + 8, out);
}

// Round 9
// 119.251 us; speedup vs baseline: 1.3568x; 1.3568x over previous
//
#include <hip/hip_runtime.h>
#include <math.h>

#define BATCH 8
#define NPRED 8192
#define MPART 2048
#define NPTS  (BATCH * NPRED)     // 65536 queries
#define MTOT  (BATCH * MPART)     // 16384 partial points
#define PPL   32                  // points per lane (2048 / 64)
#define QPW   16                  // queries per wave (SGPR-resident)
#define WPB   4                   // waves per block
#define NNBLK (NPTS / (QPW * WPB))  // 1024 blocks -> 4096 waves, 16 waves/CU
#define BASE_ALPHA 0.05f
#define EPS 1e-6f

// pt2[(b*32+i)*64 + ln] = (-2x,-2y,-2z,|b|^2) of batch-b point m = ln*32+i.
// Lane-major -> nn's per-i loads are coalesced; lane order == m order (ties!).
// near4[g] = (x,y,z,0). Also zeroes the 16 bmax slots (2 iters x 8 batches).
__global__ __launch_bounds__(256) void prep_kernel(const float* __restrict__ partial,
                                                   float4* __restrict__ pt2,
                                                   float4* __restrict__ near4,
                                                   unsigned* __restrict__ bmax) {
    const int g = blockIdx.x * 256 + threadIdx.x;   // 64 blocks cover MTOT
    const int b = g >> 11, m = g & 2047;
    const float* p = partial + 3u * (unsigned)g;
    const float x = p[0], y = p[1], z = p[2];
    const int ln = m >> 5, i = m & 31;
    pt2[(((b << 5) + i) << 6) + ln] =
        make_float4(-2.0f * x, -2.0f * y, -2.0f * z, fmaf(x, x, fmaf(y, y, z * z)));
    near4[g] = make_float4(x, y, z, 0.0f);
    if (g < 16) bmax[g] = 0u;
}

// One wave owns 16 queries (coords in SGPRs via wave-uniform s_load) and scans
// the batch's 2048 points: outer loop over its lane's 32 points (1 coalesced
// dwordx4 each), inner fully-unrolled over the 16 queries (3 fma + cmp +
// 2 cndmask; 96 VALU per 16B load). h = |b|^2 - 2a.b is order-identical to d^2.
// Cross-lane argmin: f32-min butterfly + ballot; lowest set lane = lowest m
// chunk, in-lane strict '<' keeps earliest i => exact first-occurrence argmin.
__global__ __launch_bounds__(256, 4) void nn_kernel(
    const float* __restrict__ src,       // [B,N,3] query positions
    const float4* __restrict__ pt2,      // [MTOT] lane-major transformed points
    float* __restrict__ md_out,          // [NPTS]
    int*   __restrict__ idx_out,         // [NPTS] (index within batch)
    unsigned* __restrict__ bmax)         // [BATCH] max(min_dist) as uint bits
{
    __shared__ float sm[WPB];
    const int lane = threadIdx.x & 63;
    const int wave = threadIdx.x >> 6;
    int wgi = (blockIdx.x << 2) + wave;
    wgi = __builtin_amdgcn_readfirstlane(wgi);   // provably wave-uniform
    const int qbase = wgi << 4;                  // this wave's 16 queries
    const int b = qbase >> 13;                   // batch

    // 48 query coords, wave-uniform -> s_load into SGPRs.
    const float* __restrict__ qsrc = src + 3 * qbase;
    float qx[QPW], qy[QPW], qz[QPW];
    #pragma unroll
    for (int q = 0; q < QPW; ++q) {
        qx[q] = qsrc[3 * q + 0];
        qy[q] = qsrc[3 * q + 1];
        qz[q] = qsrc[3 * q + 2];
    }

    float best[QPW]; int bi[QPW];
    #pragma unroll
    for (int q = 0; q < QPW; ++q) { best[q] = 1e30f; bi[q] = 0; }

    // My lane's 32 points, one load per outer iteration (stride 1 KB, coalesced).
    const float4* __restrict__ psrc = pt2 + (b << 11) + lane;
    #pragma unroll 4
    for (int i = 0; i < PPL; ++i) {
        const float4 P = psrc[i << 6];
        #pragma unroll
        for (int q = 0; q < QPW; ++q) {
            const float d = fmaf(P.x, qx[q], fmaf(P.y, qy[q], fmaf(P.z, qz[q], P.w)));
            if (d < best[q]) { best[q] = d; bi[q] = i; }   // strict <: earliest i
        }
    }

    // Per-query cross-lane argmin + result scatter (lane q keeps query q).
    float res_md = 0.0f; int res_idx = 0; float wmax = 0.0f;
    #pragma unroll
    for (int q = 0; q < QPW; ++q) {
        const float h = best[q];
        float hmin = h;
        #pragma unroll
        for (int o = 1; o < 64; o <<= 1)
            hmin = fminf(hmin, __shfl_xor(hmin, o, 64));
        const unsigned long long mask = __ballot(h == hmin);  // >=1 bit set
        const int L = (int)__builtin_ctzll(mask);             // lowest lane = lowest m
        const int m = (L << 5) | __shfl(bi[q], L, 64);
        const float a2 = fmaf(qx[q], qx[q], fmaf(qy[q], qy[q], qz[q] * qz[q]));
        const float md = sqrtf(fmaxf(hmin + a2, 0.0f));
        wmax = fmaxf(wmax, md);
        if (lane == q) { res_md = md; res_idx = m; }
    }
    if (lane < QPW) {
        md_out[qbase + lane]  = res_md;
        idx_out[qbase + lane] = res_idx;
    }

    // Per-block max -> 1 atomic (nonneg float bits are uint-ordered; exact).
    if (lane == 0) sm[wave] = wmax;
    __syncthreads();
    if (threadIdx.x == 0) {
        const float m4 = fmaxf(fmaxf(sm[0], sm[1]), fmaxf(sm[2], sm[3]));
        atomicMax(bmax + b, __float_as_uint(m4));
    }
}

// Blend: dst = src + alpha * (nearest - src).
__global__ __launch_bounds__(256) void update_kernel(
    const float* __restrict__ src,
    const float4* __restrict__ near4,
    const float* __restrict__ md,
    const int*   __restrict__ idx,
    const unsigned* __restrict__ bmax,
    float* __restrict__ dst)
{
    const int t = blockIdx.x * 256 + threadIdx.x;
    const int b = t >> 13;
    const float maxv = __uint_as_float(bmax[b]);
    const float alpha = BASE_ALPHA * (2.0f - md[t] / (maxv + EPS));
    const float4 nb = near4[(b << 11) + idx[t]];
    const float* p = src + 3u * (unsigned)t;
    const float px = p[0], py = p[1], pz = p[2];
    float* o = dst + 3u * (unsigned)t;
    o[0] = fmaf(alpha, nb.x - px, px);
    o[1] = fmaf(alpha, nb.y - py, py);
    o[2] = fmaf(alpha, nb.z - pz, pz);
}

extern "C" void kernel_launch(void* const* d_in, const int* in_sizes, int n_in,
                              void* d_out, int out_size, void* d_ws, size_t ws_size,
                              hipStream_t stream) {
    const float* pred    = (const float*)d_in[0];   // [8,8192,3] fp32
    const float* partial = (const float*)d_in[1];   // [8,2048,3] fp32
    float* out = (float*)d_out;

    char* ws = (char*)d_ws;
    float4*   pt2   = (float4*)ws;                  // 256 KB lane-major points
    float4*   near4 = (float4*)(ws + 262144);       // 256 KB
    float*    ref1  = (float*)(ws + 524288);        // 768 KB refined-1
    float*    md1   = (float*)(ws + 1310720);       // 256 KB
    int*      idx1  = (int*)(ws + 1572864);         // 256 KB
    unsigned* bmax  = (unsigned*)(ws + 1835008);    // 16 uints (2 iters x 8)

    prep_kernel<<<MTOT / 256, 256, 0, stream>>>(partial, pt2, near4, bmax);

    // Iter 1: NN on pred, then blend pred -> ref1
    nn_kernel<<<NNBLK, 256, 0, stream>>>(pred, pt2, md1, idx1, bmax);
    update_kernel<<<NPTS / 256, 256, 0, stream>>>(pred, near4, md1, idx1, bmax, ref1);

    // Iter 2: NN on ref1, then blend ref1 -> out
    nn_kernel<<<NNBLK, 256, 0, stream>>>(ref1, pt2, md1, idx1, bmax + 8);
    update_kernel<<<NPTS / 256, 256, 0, stream>>>(ref1, near4, md1, idx1, bmax + 8, out);
}